// Round 4
// baseline (201.069 us; speedup 1.0000x reference)
//
#include <hip/hip_runtime.h>
#include <math.h>

// Problem constants
constexpr int NROI = 2048;  // N
constexpr int CDIM = 1024;  // C
constexpr int NG   = 16;    // groups
constexpr int DH   = 64;    // per-group dim

typedef __attribute__((ext_vector_type(8))) short short8;    // 8 bf16 (4 VGPRs)
typedef __attribute__((ext_vector_type(4))) float floatx4;   // MFMA C/D frag

#define MFMA_BF16(a, b, c) __builtin_amdgcn_mfma_f32_16x16x32_bf16((a), (b), (c), 0, 0, 0)

// fp32 -> bf16 round-to-nearest-even
__device__ __forceinline__ short f2bf(float f) {
  unsigned u = __float_as_uint(f);
  unsigned r = 0x7fffu + ((u >> 16) & 1u);
  return (short)((u + r) >> 16);
}
__device__ __forceinline__ unsigned pack2(float a, float b) {
  return (unsigned)(unsigned short)f2bf(a) | ((unsigned)(unsigned short)f2bf(b) << 16);
}

// async global->LDS, 16B per lane; LDS dest = wave-uniform base + lane*16
typedef __attribute__((address_space(1))) void GV;
typedef __attribute__((address_space(3))) void LV;
__device__ __forceinline__ void gl2lds16(const void* g, void* l) {
  __builtin_amdgcn_global_load_lds((GV*)g, (LV*)l, 16, 0, 0);
}

// bf16 relu on a packed short8 (sign-bit based; exact)
__device__ __forceinline__ short8 brelu(short8 v) {
  union { short8 s; unsigned u[4]; } x; x.s = v;
#pragma unroll
  for (int i = 0; i < 4; ++i) {
    unsigned m = (x.u[i] >> 15) & 0x10001u;
    x.u[i] &= ~(m * 0xFFFFu);
  }
  return x.s;
}

// ---------------- conversion: fp32 -> bf16 ----------------
__global__ __launch_bounds__(256) void convert_kernel(
    const float* __restrict__ in_x, const float* __restrict__ W0,
    const float* __restrict__ W1, const float* __restrict__ Wout,
    short* __restrict__ xin_b, short* __restrict__ W0b,
    short* __restrict__ W1b, short* __restrict__ Woutb)
{
  const int i = blockIdx.x * 256 + threadIdx.x;   // float4 units
  {
    const float4 v = ((const float4*)in_x)[i];
    uint2 u; u.x = pack2(v.x, v.y); u.y = pack2(v.z, v.w);
    ((uint2*)xin_b)[i] = u;
  }
  if (i < 262144) {
    float4 v = ((const float4*)W0)[i];
    uint2 u; u.x = pack2(v.x, v.y); u.y = pack2(v.z, v.w);
    ((uint2*)W0b)[i] = u;
    v = ((const float4*)W1)[i];
    u.x = pack2(v.x, v.y); u.y = pack2(v.z, v.w);
    ((uint2*)W1b)[i] = u;
    v = ((const float4*)Wout)[i];
    u.x = pack2(v.x, v.y); u.y = pack2(v.z, v.w);
    ((uint2*)Woutb)[i] = u;
  }
}

// ---------------- iou+1e-6 matrix (bf16); symmetric, so (q,k) == (k,q) ----------------
__global__ __launch_bounds__(256) void iou_kernel(const float* __restrict__ rois,
                                                  unsigned short* __restrict__ biasb)
{
  const int q = blockIdx.y;
  const int k = blockIdx.x * 256 + threadIdx.x;
  const float qx1 = rois[q * 5 + 1], qy1 = rois[q * 5 + 2];
  const float qx2 = rois[q * 5 + 3], qy2 = rois[q * 5 + 4];
  const float qa = (qx2 - qx1 + 1.f) * (qy2 - qy1 + 1.f);
  const float kx1 = rois[k * 5 + 1], ky1 = rois[k * 5 + 2];
  const float kx2 = rois[k * 5 + 3], ky2 = rois[k * 5 + 4];
  const float ka = (kx2 - kx1 + 1.f) * (ky2 - ky1 + 1.f);
  float iw = fminf(qx2, kx2) - fmaxf(qx1, kx1) + 1.f;
  float ih = fminf(qy2, ky2) - fmaxf(qy1, ky1) + 1.f;
  iw = fmaxf(iw, 0.f); ih = fmaxf(ih, 0.f);
  const float inter = iw * ih;
  const float iou = inter / (qa + ka - inter);
  biasb[(size_t)q * NROI + k] = (unsigned short)f2bf(iou + 1e-6f);
}

// ---------------- fused GEMM A: t0 = relu(x)@W0^T+b0  AND  zT = (x@Wout^T)^T ----------------
// blockIdx.x < 16 -> W0 half (relu on A, bias, row-major out); else Wout half (transposed out).
__global__ __launch_bounds__(256) void gemm_fusedA(
    const short* __restrict__ A, const short* __restrict__ BW0,
    const short* __restrict__ BWout, const float* __restrict__ b0,
    short* __restrict__ t0b, short* __restrict__ zT)
{
  __shared__ short As[8 * 512];
  __shared__ short Bs[8 * 512];
  const int isW0 = blockIdx.x < 16;
  const int col0 = (blockIdx.x & 15) * 64;
  const short* B = isW0 ? BW0 : BWout;
  const int t = threadIdx.x, w = t >> 6, lane = t & 63;
  const int wm = w >> 1, wn = w & 1;
  const int row0 = blockIdx.y * 64;
  const int rlo = lane & 15, khi = (lane >> 4) * 8;

  floatx4 acc[2][2];
#pragma unroll
  for (int i = 0; i < 2; ++i)
#pragma unroll
    for (int j = 0; j < 2; ++j) acc[i][j] = (floatx4){0.f, 0.f, 0.f, 0.f};

  for (int k0 = 0; k0 < CDIM; k0 += 64) {
    __syncthreads();
#pragma unroll
    for (int kh = 0; kh < 2; ++kh) {
      gl2lds16(A + (size_t)(row0 + w * 16 + rlo) * CDIM + k0 + kh * 32 + khi,
               &As[(w * 2 + kh) * 512]);
      gl2lds16(B + (size_t)(col0 + w * 16 + rlo) * CDIM + k0 + kh * 32 + khi,
               &Bs[(w * 2 + kh) * 512]);
    }
    __syncthreads();
#pragma unroll
    for (int kh = 0; kh < 2; ++kh) {
      short8 a0 = *(const short8*)&As[((wm * 2 + 0) * 2 + kh) * 512 + lane * 8];
      short8 a1 = *(const short8*)&As[((wm * 2 + 1) * 2 + kh) * 512 + lane * 8];
      if (isW0) { a0 = brelu(a0); a1 = brelu(a1); }
      const short8 b0f = *(const short8*)&Bs[((wn * 2 + 0) * 2 + kh) * 512 + lane * 8];
      const short8 b1f = *(const short8*)&Bs[((wn * 2 + 1) * 2 + kh) * 512 + lane * 8];
      acc[0][0] = MFMA_BF16(a0, b0f, acc[0][0]);
      acc[0][1] = MFMA_BF16(a0, b1f, acc[0][1]);
      acc[1][0] = MFMA_BF16(a1, b0f, acc[1][0]);
      acc[1][1] = MFMA_BF16(a1, b1f, acc[1][1]);
    }
  }

  const int colL = lane & 15, qq = lane >> 4;
  float bj[2] = {0.f, 0.f};
  if (isW0) {
    bj[0] = b0[col0 + wn * 32 + colL];
    bj[1] = b0[col0 + wn * 32 + 16 + colL];
  }
#pragma unroll
  for (int i = 0; i < 2; ++i)
#pragma unroll
    for (int j = 0; j < 2; ++j)
#pragma unroll
      for (int r = 0; r < 4; ++r) {
        const int row = row0 + wm * 32 + i * 16 + qq * 4 + r;
        const int cc  = col0 + wn * 32 + j * 16 + colL;
        const short bv = f2bf(acc[i][j][r] + bj[j]);
        if (isW0) t0b[(size_t)row * CDIM + cc] = bv;
        else      zT[(size_t)cc * NROI + row] = bv;
      }
}

// ---------------- GEMM1: xb = relu(t0) @ W1^T + b1 (bf16 row-major) ----------------
__global__ __launch_bounds__(256) void gemm_relu_nt(
    const short* __restrict__ A, const short* __restrict__ B,
    const float* __restrict__ bias, short* __restrict__ C)
{
  __shared__ short As[8 * 512];
  __shared__ short Bs[8 * 512];
  const int t = threadIdx.x, w = t >> 6, lane = t & 63;
  const int wm = w >> 1, wn = w & 1;
  const int row0 = blockIdx.y * 64, col0 = blockIdx.x * 64;
  const int rlo = lane & 15, khi = (lane >> 4) * 8;

  floatx4 acc[2][2];
#pragma unroll
  for (int i = 0; i < 2; ++i)
#pragma unroll
    for (int j = 0; j < 2; ++j) acc[i][j] = (floatx4){0.f, 0.f, 0.f, 0.f};

  for (int k0 = 0; k0 < CDIM; k0 += 64) {
    __syncthreads();
#pragma unroll
    for (int kh = 0; kh < 2; ++kh) {
      gl2lds16(A + (size_t)(row0 + w * 16 + rlo) * CDIM + k0 + kh * 32 + khi,
               &As[(w * 2 + kh) * 512]);
      gl2lds16(B + (size_t)(col0 + w * 16 + rlo) * CDIM + k0 + kh * 32 + khi,
               &Bs[(w * 2 + kh) * 512]);
    }
    __syncthreads();
#pragma unroll
    for (int kh = 0; kh < 2; ++kh) {
      short8 a0 = *(const short8*)&As[((wm * 2 + 0) * 2 + kh) * 512 + lane * 8];
      short8 a1 = *(const short8*)&As[((wm * 2 + 1) * 2 + kh) * 512 + lane * 8];
      a0 = brelu(a0); a1 = brelu(a1);
      const short8 b0f = *(const short8*)&Bs[((wn * 2 + 0) * 2 + kh) * 512 + lane * 8];
      const short8 b1f = *(const short8*)&Bs[((wn * 2 + 1) * 2 + kh) * 512 + lane * 8];
      acc[0][0] = MFMA_BF16(a0, b0f, acc[0][0]);
      acc[0][1] = MFMA_BF16(a0, b1f, acc[0][1]);
      acc[1][0] = MFMA_BF16(a1, b0f, acc[1][0]);
      acc[1][1] = MFMA_BF16(a1, b1f, acc[1][1]);
    }
  }

  const int colL = lane & 15, qq = lane >> 4;
  float bj[2];
  bj[0] = bias[col0 + wn * 32 + colL];
  bj[1] = bias[col0 + wn * 32 + 16 + colL];
#pragma unroll
  for (int i = 0; i < 2; ++i)
#pragma unroll
    for (int j = 0; j < 2; ++j)
#pragma unroll
      for (int r = 0; r < 4; ++r) {
        const int row = row0 + wm * 32 + i * 16 + qq * 4 + r;
        const int cc  = col0 + wn * 32 + j * 16 + colL;
        C[(size_t)row * CDIM + cc] = f2bf(acc[i][j][r] + bj[j]);
      }
}

// ---------------- split-K MFMA flash attention ----------------
// P = exp(s/8)*(iou+1e-6): linear in keys -> 2-way key split merges with plain sums.
// Split 0 -> fp32 partial in O0 (d_out); split 1 -> bf16 partial in O1 (ws).
// Bias read transposed (symmetric matrix) as uint2 (4 q per load), reg double-buffered.
__global__ __launch_bounds__(512) void attn_split(
    const short* __restrict__ Xb,             // (N,C) bf16 embedded x
    const short* __restrict__ ZTb,            // (C,N) bf16 V, transposed
    const unsigned short* __restrict__ biasb, // (N,N) bf16 iou+1e-6 (symmetric)
    float* __restrict__ O0, short* __restrict__ O1,
    float* __restrict__ lsums)                // [2][NG][NROI]
{
  const int g  = blockIdx.y;
  const int n0 = blockIdx.x * 128;
  const int sp = blockIdx.z;
  const int mbase = sp * 1024;
  const int t = threadIdx.x, w = t >> 6, lane = t & 63;
  const int col = lane & 15, qq = lane >> 4;
  const int t16 = (w >> 1) * 16, h32 = (w & 1) * 32;
  const int rlo = lane & 15, khi = (lane >> 4) * 8;

  __shared__ short Kf[2][8 * 512];
  __shared__ short Vf[2][8 * 512];
  __shared__ short Pf[8 * 1024];

  const size_t qoff = (size_t)(n0 + w * 16 + col) * CDIM + g * DH;
  const short8 qf0 = *(const short8*)(Xb + qoff + qq * 8);
  const short8 qf1 = *(const short8*)(Xb + qoff + 32 + qq * 8);

  floatx4 oc[4];
#pragma unroll
  for (int dt = 0; dt < 4; ++dt) oc[dt] = (floatx4){0.f, 0.f, 0.f, 0.f};
  float lsum[4] = {0.f, 0.f, 0.f, 0.f};

  const int qrow0 = n0 + w * 16 + qq * 4;   // first of this lane's 4 q rows

  // bias regs for iter 0 (transposed read: bias[k][q..q+3])
  uint2 bbc[4], bbn[4];
#pragma unroll
  for (int ct = 0; ct < 4; ++ct)
    bbc[ct] = *(const uint2*)(biasb + (size_t)(mbase + ct * 16 + col) * NROI + qrow0);

  // stage tile 0
  gl2lds16(Xb + (size_t)(mbase + t16 + rlo) * CDIM + g * DH + h32 + khi, &Kf[0][w * 512]);
  gl2lds16(ZTb + (size_t)(g * DH + t16 + rlo) * NROI + mbase + h32 + khi, &Vf[0][w * 512]);
  __syncthreads();

  for (int it = 0; it < 16; ++it) {
    const int p = it & 1;
    if (it < 15) {
      const int m1 = mbase + (it + 1) * 64;
      gl2lds16(Xb + (size_t)(m1 + t16 + rlo) * CDIM + g * DH + h32 + khi,
               &Kf[1 - p][w * 512]);
      gl2lds16(ZTb + (size_t)(g * DH + t16 + rlo) * NROI + m1 + h32 + khi,
               &Vf[1 - p][w * 512]);
#pragma unroll
      for (int ct = 0; ct < 4; ++ct)
        bbn[ct] = *(const uint2*)(biasb + (size_t)(m1 + ct * 16 + col) * NROI + qrow0);
    }

    // S = Q K^T
    floatx4 sc[4];
#pragma unroll
    for (int ct = 0; ct < 4; ++ct) {
      const short8 b0 = *(const short8*)&Kf[p][(ct * 2 + 0) * 512 + lane * 8];
      const short8 b1 = *(const short8*)&Kf[p][(ct * 2 + 1) * 512 + lane * 8];
      floatx4 z4 = (floatx4){0.f, 0.f, 0.f, 0.f};
      z4 = MFMA_BF16(qf0, b0, z4);
      z4 = MFMA_BF16(qf1, b1, z4);
      sc[ct] = z4;
    }

    // P = exp(s/8) * (iou+1e-6)
#pragma unroll
    for (int ct = 0; ct < 4; ++ct) {
      const unsigned ux = bbc[ct].x, uy = bbc[ct].y;
      sc[ct][0] = __expf(sc[ct][0] * 0.125f) * __uint_as_float(ux << 16);
      sc[ct][1] = __expf(sc[ct][1] * 0.125f) * __uint_as_float(ux & 0xFFFF0000u);
      sc[ct][2] = __expf(sc[ct][2] * 0.125f) * __uint_as_float(uy << 16);
      sc[ct][3] = __expf(sc[ct][3] * 0.125f) * __uint_as_float(uy & 0xFFFF0000u);
    }
#pragma unroll
    for (int r = 0; r < 4; ++r)
      lsum[r] += sc[0][r] + sc[1][r] + sc[2][r] + sc[3][r];

    // P: C-layout -> A-layout via wave-private LDS roundtrip; then O += P V
    {
      short* pw = &Pf[w * 1024];
#pragma unroll
      for (int ct = 0; ct < 4; ++ct) {
        const int key = ct * 16 + col;
        const int base = (key >> 5) * 512 + (key & 7);
#pragma unroll
        for (int r = 0; r < 4; ++r) {
          const int dl = (4 * qq + r) + ((key >> 3) & 3) * 16;
          pw[base + dl * 8] = f2bf(sc[ct][r]);
        }
      }
      const short8 pa0 = *(const short8*)&pw[0 * 512 + lane * 8];
      const short8 pa1 = *(const short8*)&pw[1 * 512 + lane * 8];
#pragma unroll
      for (int dt = 0; dt < 4; ++dt) {
        const short8 v0 = *(const short8*)&Vf[p][(dt * 2 + 0) * 512 + lane * 8];
        const short8 v1 = *(const short8*)&Vf[p][(dt * 2 + 1) * 512 + lane * 8];
        oc[dt] = MFMA_BF16(pa0, v0, oc[dt]);
        oc[dt] = MFMA_BF16(pa1, v1, oc[dt]);
      }
    }
    __syncthreads();   // swap-safe point; drains prefetch (and bias regs)
#pragma unroll
    for (int ct = 0; ct < 4; ++ct) bbc[ct] = bbn[ct];
  }

  // reduce row sums across the 16 col-lanes
#pragma unroll
  for (int r = 0; r < 4; ++r) {
    float s = lsum[r];
    s += __shfl_xor(s, 1); s += __shfl_xor(s, 2);
    s += __shfl_xor(s, 4); s += __shfl_xor(s, 8);
    lsum[r] = s;
  }
  if (col == 0) {
#pragma unroll
    for (int r = 0; r < 4; ++r)
      lsums[sp * (NG * NROI) + g * NROI + qrow0 + r] = lsum[r];
  }
  if (sp == 0) {
#pragma unroll
    for (int dt = 0; dt < 4; ++dt)
#pragma unroll
      for (int r = 0; r < 4; ++r)
        O0[(size_t)(qrow0 + r) * CDIM + g * DH + dt * 16 + col] = oc[dt][r];
  } else {
#pragma unroll
    for (int dt = 0; dt < 4; ++dt)
#pragma unroll
      for (int r = 0; r < 4; ++r)
        O1[(size_t)(qrow0 + r) * CDIM + g * DH + dt * 16 + col] = f2bf(oc[dt][r]);
  }
}

// ---------------- merge: out = (O0 + O1)/(l0+l1) + bout ----------------
__global__ __launch_bounds__(256) void merge_kernel(
    const float* __restrict__ O0, const short* __restrict__ O1,
    const float* __restrict__ lsums, const float* __restrict__ bout,
    float* __restrict__ Out)
{
  const int i = blockIdx.x * 256 + threadIdx.x;   // float4 index
  const int base = i * 4, q = base >> 10, c = base & 1023, g = c >> 6;
  const float l = lsums[g * NROI + q] + lsums[NG * NROI + g * NROI + q];
  const float linv = 1.f / l;
  const float4 o0 = ((const float4*)O0)[i];
  const uint2 o1 = ((const uint2*)O1)[i];
  const float4 bo = *(const float4*)(bout + c);
  float4 o;
  o.x = (o0.x + __uint_as_float(o1.x << 16))          * linv + bo.x;
  o.y = (o0.y + __uint_as_float(o1.x & 0xFFFF0000u))  * linv + bo.y;
  o.z = (o0.z + __uint_as_float(o1.y << 16))          * linv + bo.z;
  o.w = (o0.w + __uint_as_float(o1.y & 0xFFFF0000u))  * linv + bo.w;
  ((float4*)Out)[i] = o;
}

extern "C" void kernel_launch(void* const* d_in, const int* in_sizes, int n_in,
                              void* d_out, int out_size, void* d_ws, size_t ws_size,
                              hipStream_t stream) {
  const float* in_x = (const float*)d_in[0];
  const float* rois = (const float*)d_in[1];
  const float* W0   = (const float*)d_in[2];
  const float* b0   = (const float*)d_in[3];
  const float* W1   = (const float*)d_in[4];
  const float* b1   = (const float*)d_in[5];
  const float* Wout = (const float*)d_in[6];  // (G,D,C) flat == (C,C) row-major
  const float* bout = (const float*)d_in[7];
  char* w8 = (char*)d_ws;

  // ws layout (22 MB, liveness-packed; R3 proved ws >= 22 MB):
  //   [0,4M)   xin_b  -> xb (gemm1 out)
  //   [4,6M)   W0b  \
  //   [6,8M)   Woutb > dead after gemm_fusedA -> biasb occupies [4,12M)
  //   [8,12M)  (bias tail)
  //   [12,16M) zT
  //   [16,20M) O1 (bf16 split-1 partial)
  //   [20,22M) W1b -> lsums (256 KB) after gemm1
  // t0b (bf16) and O0 (fp32 split-0 partial) live in d_out; merge rewrites d_out.
  short* xin_b = (short*)w8;
  short* W0b   = (short*)(w8 + (4u << 20));
  short* Woutb = (short*)(w8 + (6u << 20));
  unsigned short* biasb = (unsigned short*)(w8 + (4u << 20));
  short* zT    = (short*)(w8 + (12u << 20));
  short* O1    = (short*)(w8 + (16u << 20));
  short* W1b   = (short*)(w8 + (20u << 20));
  float* lsums = (float*)(w8 + (20u << 20));
  short* xb  = xin_b;
  short* t0b = (short*)d_out;
  float* O0  = (float*)d_out;

  convert_kernel<<<2048, 256, 0, stream>>>(in_x, W0, W1, Wout,
                                           xin_b, W0b, W1b, Woutb);
  // fused: t0 = relu(x)@W0^T+b0 (cols 0..1023) and zT = (x@Wout^T)^T (cols 1024..2047)
  gemm_fusedA<<<dim3(32, 32), 256, 0, stream>>>(xin_b, W0b, Woutb, b0, t0b, zT);
  // iou AFTER gemm_fusedA (bias overwrites W0b/Woutb)
  iou_kernel<<<dim3(NROI / 256, NROI), 256, 0, stream>>>(rois, biasb);
  // xb = relu(t0)@W1^T + b1   (kills xin_b; then W1b is dead -> lsums)
  gemm_relu_nt<<<dim3(16, 32), 256, 0, stream>>>(t0b, W1b, b1, xb);
  // 2-way split-K flash attention
  attn_split<<<dim3(NROI / 128, NG, 2), 512, 0, stream>>>(xb, zT, biasb, O0, O1, lsums);
  // normalize + combine + bout
  merge_kernel<<<2048, 256, 0, stream>>>(O0, O1, lsums, bout, (float*)d_out);
}